// Round 15
// baseline (141.285 us; speedup 1.0000x reference)
//
#include <hip/hip_runtime.h>

typedef _Float16 half8  __attribute__((ext_vector_type(8)));
typedef _Float16 half2v __attribute__((ext_vector_type(2)));
typedef __fp16   fp16x2 __attribute__((ext_vector_type(2)));
typedef float    f32x4  __attribute__((ext_vector_type(4)));
typedef float    f32x16 __attribute__((ext_vector_type(16)));

// 32x32x16 fragment layout:
//   A/B: value W[k][m] at lane l, elem j:  m = mt*32 + (l&31),
//        k = kt*32 + sl*16 + 8*(j>>2) + 4*(l>>5) + (j&3)
//   C/D: col = lane&31 (sample), row = (reg&3) + 8*(reg>>2) + 4*(lane>>5)
//   => D regs 0..7 == next-layer B-frag slice 0, regs 8..15 == slice 1 (same j).
// ws blob (halfs): L1..L3 at (i-1)*16384 + ((mt*4+kt)*2+sl)*512 + lane*8
//   W4^T at 49152 + (kt*2+sl)*512; W0ext (k=0 -> W0, k=1 -> b0) at 53248 + mt*512

__global__ __launch_bounds__(256) void prep_kernel(
    const float* __restrict__ W1, const float* __restrict__ W2,
    const float* __restrict__ W3, const float* __restrict__ W4,
    const float* __restrict__ W0, const float* __restrict__ b0,
    _Float16* __restrict__ out)
{
    int t = blockIdx.x * blockDim.x + threadIdx.x;
    if (t >= 6912) return;
    int lane = t & 63;
    int frag = t >> 6;                 // 0..107
    int m31  = lane & 31;
    int klo  = (lane >> 5) << 2;       // 4*(lane>>5)

    if (frag < 96) {
        int ly = frag >> 5, f = frag & 31;
        const float* W = (ly == 0) ? W1 : (ly == 1) ? W2 : W3;
        int mt = f >> 3, kt = (f >> 1) & 3, sl = f & 1;
        _Float16* dst = out + ly * 16384 + f * 512 + lane * 8;
        int m = mt * 32 + m31;
        int kbase = kt * 32 + sl * 16 + klo;
#pragma unroll
        for (int j = 0; j < 8; ++j) {
            int k = kbase + 8 * (j >> 2) + (j & 3);
            dst[j] = (_Float16)W[k * 128 + m];
        }
    } else if (frag < 104) {
        int f = frag - 96;             // kt*2+sl
        int kt = f >> 1, sl = f & 1;
        _Float16* dst = out + 49152 + f * 512 + lane * 8;
        int kbase = kt * 32 + sl * 16 + klo;
#pragma unroll
        for (int j = 0; j < 8; ++j) {
            int k = kbase + 8 * (j >> 2) + (j & 3);
            float v = (m31 < 14) ? W4[k * 14 + m31] : 0.0f;
            dst[j] = (_Float16)v;
        }
    } else {
        int mt = frag - 104;
        _Float16* dst = out + 53248 + mt * 512 + lane * 8;
        int m = mt * 32 + m31;
#pragma unroll
        for (int j = 0; j < 8; ++j) {
            int k = 8 * (j >> 2) + klo + (j & 3);
            float v = (k == 0) ? W0[m] : (k == 1) ? b0[m] : 0.0f;
            dst[j] = (_Float16)v;
        }
    }
}

static __device__ __forceinline__ half2v relu_cvt2(float a, float b) {
    fp16x2 h = __builtin_amdgcn_cvt_pkrtz(a, b);
    fp16x2 zz = {(__fp16)0.0f, (__fp16)0.0f};
    h = __builtin_elementwise_max(h, zz);
    return __builtin_bit_cast(half2v, h);
}

// acc (16 f32) -> two B-frag slices (relu + cvt), elementwise (same j index).
static __device__ __forceinline__ void pack_frags(const f32x16& acc, half8& s0, half8& s1) {
#pragma unroll
    for (int p = 0; p < 4; ++p) {
        half2v lo = relu_cvt2(acc[2 * p],     acc[2 * p + 1]);
        half2v hi = relu_cvt2(acc[8 + 2 * p], acc[8 + 2 * p + 1]);
        s0[2 * p] = lo[0]; s0[2 * p + 1] = lo[1];
        s1[2 * p] = hi[0]; s1[2 * p + 1] = hi[1];
    }
}

// One m-tile (32 features) of a hidden 128->128 layer: 16 MFMA 32x32x16
// (2 groups x 8 K-slices), bias as C-init of the first slice.
template<int MT>
static __device__ __forceinline__ void hidden_stage(
    const half8 (&bin)[2][4][2], half8 (&bout)[2][4][2],
    const float* __restrict__ bias, const _Float16* __restrict__ Al,
    int lane, int klo)
{
    half8 a[4][2];
#pragma unroll
    for (int kt = 0; kt < 4; ++kt)
#pragma unroll
        for (int sl = 0; sl < 2; ++sl)
            a[kt][sl] = *(const half8*)(Al + ((MT * 4 + kt) * 2 + sl) * 512 + lane * 8);

    f32x16 bc;
    int base = MT * 32 + klo;
#pragma unroll
    for (int c = 0; c < 4; ++c) {
        f32x4 t = *(const f32x4*)(bias + base + 8 * c);
#pragma unroll
        for (int e = 0; e < 4; ++e) bc[c * 4 + e] = t[e];
    }

    __builtin_amdgcn_s_setprio(1);
    f32x16 acc0 = __builtin_amdgcn_mfma_f32_32x32x16_f16(a[0][0], bin[0][0][0], bc, 0, 0, 0);
    f32x16 acc1 = __builtin_amdgcn_mfma_f32_32x32x16_f16(a[0][0], bin[1][0][0], bc, 0, 0, 0);
#pragma unroll
    for (int kt = 0; kt < 4; ++kt)
#pragma unroll
        for (int sl = 0; sl < 2; ++sl) {
            if (kt == 0 && sl == 0) continue;
            acc0 = __builtin_amdgcn_mfma_f32_32x32x16_f16(a[kt][sl], bin[0][kt][sl], acc0, 0, 0, 0);
            acc1 = __builtin_amdgcn_mfma_f32_32x32x16_f16(a[kt][sl], bin[1][kt][sl], acc1, 0, 0, 0);
        }
    __builtin_amdgcn_s_setprio(0);

    pack_frags(acc0, bout[0][MT][0], bout[0][MT][1]);
    pack_frags(acc1, bout[1][MT][0], bout[1][MT][1]);
}

__global__ __launch_bounds__(256, 2) void nflow_kernel(
    const float* __restrict__ x, const float* __restrict__ z,
    const float* __restrict__ b1, const float* __restrict__ b2,
    const float* __restrict__ b3, const float* __restrict__ b4v,
    const _Float16* __restrict__ Af, float* __restrict__ y, int N)
{
    __shared__ float phis[256][20];   // 20480 B; stride 20 f32

    const int tid  = threadIdx.x;
    const int lane = tid & 63;
    const int wid  = tid >> 6;
    const int m31  = lane & 31;
    const int klo  = (lane >> 5) << 2;
    const int sbase = blockIdx.x * 256 + wid * 64;
    const int gs    = blockIdx.x * 256 + tid;

    float zv = (gs < N) ? z[gs] : 0.0f;   // hoisted

    half8 binA[2][4][2], binB[2][4][2];   // [group][ktile][slice]

    // ---- layer 0: h0 = relu([x,1]·[W0;b0]) via 8 MFMA (K=2 effective)
    {
        half8 bx[2];
#pragma unroll
        for (int g = 0; g < 2; ++g) {
            int s = sbase + g * 32 + m31;
            float xv = (s < N) ? x[s] : 0.0f;
            half8 t = {};
            if (lane < 32) { t[0] = (_Float16)xv; t[1] = (_Float16)1.0f; }
            bx[g] = t;
        }
        const f32x16 zero16 = {};
#pragma unroll
        for (int mt = 0; mt < 4; ++mt) {
            half8 a0 = *(const half8*)(Af + 53248 + mt * 512 + lane * 8);
            __builtin_amdgcn_s_setprio(1);
            f32x16 acc0 = __builtin_amdgcn_mfma_f32_32x32x16_f16(a0, bx[0], zero16, 0, 0, 0);
            f32x16 acc1 = __builtin_amdgcn_mfma_f32_32x32x16_f16(a0, bx[1], zero16, 0, 0, 0);
            __builtin_amdgcn_s_setprio(0);
            pack_frags(acc0, binA[0][mt][0], binA[0][mt][1]);
            pack_frags(acc1, binA[1][mt][0], binA[1][mt][1]);
        }
    }

    // ---- hidden layers 1..3 (ping-pong buffers)
    hidden_stage<0>(binA, binB, b1, Af,         lane, klo);
    hidden_stage<1>(binA, binB, b1, Af,         lane, klo);
    hidden_stage<2>(binA, binB, b1, Af,         lane, klo);
    hidden_stage<3>(binA, binB, b1, Af,         lane, klo);

    hidden_stage<0>(binB, binA, b2, Af + 16384, lane, klo);
    hidden_stage<1>(binB, binA, b2, Af + 16384, lane, klo);
    hidden_stage<2>(binB, binA, b2, Af + 16384, lane, klo);
    hidden_stage<3>(binB, binA, b2, Af + 16384, lane, klo);

    hidden_stage<0>(binA, binB, b3, Af + 32768, lane, klo);
    hidden_stage<1>(binA, binB, b3, Af + 32768, lane, klo);
    hidden_stage<2>(binA, binB, b3, Af + 32768, lane, klo);
    hidden_stage<3>(binA, binB, b3, Af + 32768, lane, klo);

    // ---- layer 4: phi = W4^T·h + b4 (one m-tile, features 0..13 in regs 0..7)
    {
        half8 a4[4][2];
#pragma unroll
        for (int kt = 0; kt < 4; ++kt)
#pragma unroll
            for (int sl = 0; sl < 2; ++sl)
                a4[kt][sl] = *(const half8*)(Af + 49152 + (kt * 2 + sl) * 512 + lane * 8);
        f32x16 b4c;
#pragma unroll
        for (int j = 0; j < 16; ++j) {
            int f = (j & 3) + 8 * ((j >> 2) & 1) + 16 * (j >> 3) + klo;
            b4c[j] = (f < 14) ? b4v[f] : 0.0f;
        }
        __builtin_amdgcn_s_setprio(1);
        f32x16 acc0 = __builtin_amdgcn_mfma_f32_32x32x16_f16(a4[0][0], binB[0][0][0], b4c, 0, 0, 0);
        f32x16 acc1 = __builtin_amdgcn_mfma_f32_32x32x16_f16(a4[0][0], binB[1][0][0], b4c, 0, 0, 0);
#pragma unroll
        for (int kt = 0; kt < 4; ++kt)
#pragma unroll
            for (int sl = 0; sl < 2; ++sl) {
                if (kt == 0 && sl == 0) continue;
                acc0 = __builtin_amdgcn_mfma_f32_32x32x16_f16(a4[kt][sl], binB[0][kt][sl], acc0, 0, 0, 0);
                acc1 = __builtin_amdgcn_mfma_f32_32x32x16_f16(a4[kt][sl], binB[1][kt][sl], acc1, 0, 0, 0);
            }
        __builtin_amdgcn_s_setprio(0);

        // regs 0..7 cover features: klo..klo+3 and 8+klo..11+klo
#pragma unroll
        for (int g = 0; g < 2; ++g) {
            const f32x16& ac = (g == 0) ? acc0 : acc1;
            int srow = wid * 64 + g * 32 + m31;
            f32x4 lo, hi;
#pragma unroll
            for (int e = 0; e < 4; ++e) { lo[e] = ac[e]; hi[e] = ac[4 + e]; }
            *(f32x4*)&phis[srow][klo]     = lo;
            *(f32x4*)&phis[srow][8 + klo] = hi;
        }
    }

    // NO __syncthreads: wave wid wrote phis rows [wid*64, wid*64+64) and the
    // spline threads for those rows are the same wave (intra-wave LDS order).

    // ---- RQS inverse: all 256 threads, one sample each
    if (gs < N) {
        float ph[16];
        *(f32x4*)&ph[0]  = *(const f32x4*)&phis[tid][0];
        *(f32x4*)&ph[4]  = *(const f32x4*)&phis[tid][4];
        *(f32x4*)&ph[8]  = *(const f32x4*)&phis[tid][8];
        *(f32x4*)&ph[12] = *(const f32x4*)&phis[tid][12];

        float mw = ph[0], mh = ph[5];
#pragma unroll
        for (int i = 1; i < 5; ++i) { mw = fmaxf(mw, ph[i]); mh = fmaxf(mh, ph[5 + i]); }
        float ew[5], eh[5];
        float sw = 0.f, sh = 0.f;
#pragma unroll
        for (int i = 0; i < 5; ++i) {
            ew[i] = __expf(ph[i] - mw);      sw += ew[i];
            eh[i] = __expf(ph[5 + i] - mh);  sh += eh[i];
        }
        float iw = 10.0f / sw, ih = 10.0f / sh;
        float xk[6], yk[6], dk[6];
        xk[0] = -5.0f; yk[0] = -5.0f;
#pragma unroll
        for (int i = 0; i < 5; ++i) {
            xk[i + 1] = xk[i] + ew[i] * iw;
            yk[i + 1] = yk[i] + eh[i] * ih;
        }
        dk[0] = 1.0f; dk[5] = 1.0f;
#pragma unroll
        for (int i = 0; i < 4; ++i) {
            float v = ph[10 + i];
            dk[i + 1] = 0.0001f + fmaxf(v, 0.0f) + __logf(1.0f + __expf(-fabsf(v)));
        }
        float zc = fminf(fmaxf(zv, -5.0f), 5.0f);
        int k = 0;
#pragma unroll
        for (int i = 1; i <= 4; ++i) k += (zc >= yk[i]) ? 1 : 0;
        float x0 = xk[0], x1 = xk[1], y0 = yk[0], y1 = yk[1], d0 = dk[0], d1 = dk[1];
#pragma unroll
        for (int i = 1; i < 5; ++i)
            if (k == i) { x0 = xk[i]; x1 = xk[i + 1]; y0 = yk[i]; y1 = yk[i + 1]; d0 = dk[i]; d1 = dk[i + 1]; }
        float dx = x1 - x0, dy = y1 - y0;
        float s  = dy / dx;
        float tt = zc - y0;
        float mm = d0 + d1 - 2.0f * s;
        float aa = dy * (s - d0) + tt * mm;
        float bb2 = dy * d0 - tt * mm;
        float cc = -s * tt;
        float disc = fmaxf(bb2 * bb2 - 4.0f * aa * cc, 0.0f);
        float xi   = (2.0f * cc) / (-bb2 - sqrtf(disc));
        float xin  = x0 + xi * dx;
        y[gs] = (fabsf(zv) >= 5.0f) ? zv : xin;
    }
}

extern "C" void kernel_launch(void* const* d_in, const int* in_sizes, int n_in,
                              void* d_out, int out_size, void* d_ws, size_t ws_size,
                              hipStream_t stream) {
    const float* x  = (const float*)d_in[0];
    const float* z  = (const float*)d_in[1];
    const float* W0 = (const float*)d_in[2];
    const float* b0 = (const float*)d_in[3];
    const float* W1 = (const float*)d_in[4];
    const float* b1 = (const float*)d_in[5];
    const float* W2 = (const float*)d_in[6];
    const float* b2 = (const float*)d_in[7];
    const float* W3 = (const float*)d_in[8];
    const float* b3 = (const float*)d_in[9];
    const float* W4 = (const float*)d_in[10];
    const float* b4 = (const float*)d_in[11];
    float* y = (float*)d_out;
    int N = in_sizes[0];

    _Float16* wsH = (_Float16*)d_ws;
    prep_kernel<<<27, 256, 0, stream>>>(W1, W2, W3, W4, W0, b0, wsH);
    int nblk = (N + 255) / 256;
    nflow_kernel<<<nblk, 256, 0, stream>>>(x, z, b1, b2, b3, b4, wsH, y, N);
}

// Round 16
// 124.004 us; speedup vs baseline: 1.1394x; 1.1394x over previous
//
#include <hip/hip_runtime.h>

typedef _Float16 half8 __attribute__((ext_vector_type(8)));
typedef _Float16 half2v __attribute__((ext_vector_type(2)));
typedef __fp16   fp16x2 __attribute__((ext_vector_type(2)));
typedef float    f32x4 __attribute__((ext_vector_type(4)));

// Fragment layout (validated R1..R14 end-to-end):
//   value = Wsrc[k][m] at lane l, elem j:  m = mt*16 + (l&15),
//   k = ks*32 + 16*(j>>2) + ((l>>4)<<2) + (j&3)
// ws blob (halfs), COMPACT: L1..L3 frags at (i-1)*16384 + (mt*4+ks)*512 + lane*8
//   W4^T at 49152 + ks*512; W0ext (k=0 -> W0, k=1 -> b0) at 51200 + mt*512

__global__ __launch_bounds__(256) void prep_kernel(
    const float* __restrict__ W1, const float* __restrict__ W2,
    const float* __restrict__ W3, const float* __restrict__ W4,
    const float* __restrict__ W0, const float* __restrict__ b0,
    _Float16* __restrict__ out)
{
    int t = blockIdx.x * blockDim.x + threadIdx.x;
    if (t >= 6912) return;
    int lane = t & 63;
    int frag = t >> 6;                 // 0..107
    int col  = lane & 15;
    int kq   = (lane >> 4) << 2;

    if (frag < 96) {
        int l = frag >> 5, f = frag & 31;
        const float* W = (l == 0) ? W1 : (l == 1) ? W2 : W3;
        int mt = f >> 2, ks = f & 3;
        _Float16* dst = out + l * 16384 + f * 512 + lane * 8;
        int m = mt * 16 + col;
        int kbase = ks * 32 + kq;
#pragma unroll
        for (int j = 0; j < 8; ++j) {
            int k = kbase + 16 * (j >> 2) + (j & 3);
            dst[j] = (_Float16)W[k * 128 + m];
        }
    } else if (frag < 100) {
        int ks = frag - 96;
        _Float16* dst = out + 49152 + ks * 512 + lane * 8;
        int m = col;
        int kbase = ks * 32 + kq;
#pragma unroll
        for (int j = 0; j < 8; ++j) {
            int k = kbase + 16 * (j >> 2) + (j & 3);
            float v = (m < 14) ? W4[k * 14 + m] : 0.0f;
            dst[j] = (_Float16)v;
        }
    } else {
        int mt = frag - 100;
        _Float16* dst = out + 51200 + mt * 512 + lane * 8;
        int m = mt * 16 + col;
#pragma unroll
        for (int j = 0; j < 8; ++j) {
            int k = 16 * (j >> 2) + kq + (j & 3);
            float v = (k == 0) ? W0[m] : (k == 1) ? b0[m] : 0.0f;
            dst[j] = (_Float16)v;
        }
    }
}

static __device__ __forceinline__ half2v relu_cvt2(float a, float b) {
    fp16x2 h = __builtin_amdgcn_cvt_pkrtz(a, b);
    fp16x2 zz = {(__fp16)0.0f, (__fp16)0.0f};
    h = __builtin_elementwise_max(h, zz);
    return __builtin_bit_cast(half2v, h);
}

// Rotating prefetch stage: 8 weight frags + 2 bias vectors for one mt-pair.
struct Stage {
    half8 a[2][4];
    f32x4 bv[2];
};

template<int MTP>
static __device__ __forceinline__ void load_stage(
    Stage& s, const _Float16* __restrict__ Al, const float* __restrict__ bias,
    int lane, int quad)
{
#pragma unroll
    for (int hh = 0; hh < 2; ++hh) {
#pragma unroll
        for (int ks = 0; ks < 4; ++ks)
            s.a[hh][ks] = *(const half8*)(Al + ((2 * MTP + hh) * 4 + ks) * 512 + lane * 8);
        s.bv[hh] = *(const f32x4*)(bias + (2 * MTP + hh) * 16 + quad * 4);
    }
}

// One mt-pair of a hidden layer: 16 MFMA (bias folded in as the C operand of
// the first ks), epilogue packs straight into bout[g][MTP]. setprio around
// the MFMA cluster (phase-diverse barrier-free waves -> T5 regime).
// Peak accumulator footprint: 8 x f32x4 = 32 regs.
template<int MTP>
static __device__ __forceinline__ void mfma_stage(
    const half8 (&bin)[4][4], half8 (&bout)[4][4], const Stage& s)
{
    f32x4 acc[4][2];
    __builtin_amdgcn_s_setprio(1);
#pragma unroll
    for (int hh = 0; hh < 2; ++hh)
#pragma unroll
        for (int g = 0; g < 4; ++g)
            acc[g][hh] = __builtin_amdgcn_mfma_f32_16x16x32_f16(s.a[hh][0], bin[g][0], s.bv[hh], 0, 0, 0);
#pragma unroll
    for (int ks = 1; ks < 4; ++ks)
#pragma unroll
        for (int hh = 0; hh < 2; ++hh)
#pragma unroll
            for (int g = 0; g < 4; ++g)
                acc[g][hh] = __builtin_amdgcn_mfma_f32_16x16x32_f16(s.a[hh][ks], bin[g][ks], acc[g][hh], 0, 0, 0);
    __builtin_amdgcn_s_setprio(0);
#pragma unroll
    for (int g = 0; g < 4; ++g)
#pragma unroll
        for (int p = 0; p < 4; ++p) {
            half2v hv = relu_cvt2(acc[g][p >> 1][2 * (p & 1)], acc[g][p >> 1][2 * (p & 1) + 1]);
            bout[g][MTP][2 * p]     = hv[0];
            bout[g][MTP][2 * p + 1] = hv[1];
        }
}

__global__ __launch_bounds__(256, 2) void nflow_kernel(
    const float* __restrict__ x, const float* __restrict__ z,
    const float* __restrict__ b1, const float* __restrict__ b2,
    const float* __restrict__ b3, const float* __restrict__ b4v,
    const _Float16* __restrict__ Af, float* __restrict__ y, int N)
{
    __shared__ float phis[256][20];   // 20480 B; stride 20 f32 -> conflict-free b128

    const int tid  = threadIdx.x;
    const int lane = tid & 63;
    const int wid  = tid >> 6;
    const int col  = lane & 15;
    const int quad = lane >> 4;
    const int sbase = blockIdx.x * 256 + wid * 64;
    const int gs    = blockIdx.x * 256 + tid;

    float zv = (gs < N) ? z[gs] : 0.0f;   // hoisted ~whole-kernel ahead of use

    const _Float16* A1 = Af;
    const _Float16* A2 = Af + 16384;
    const _Float16* A3 = Af + 32768;

    // ---- L0 weight frags upfront (overlaps x/z load latency)
    half8 aL0[8];
#pragma unroll
    for (int mt = 0; mt < 8; ++mt)
        aL0[mt] = *(const half8*)(Af + 51200 + mt * 512 + lane * 8);

    half8 bx[4];
#pragma unroll
    for (int g = 0; g < 4; ++g) {
        int s = sbase + g * 16 + col;
        float xv = (s < N) ? x[s] : 0.0f;
        half8 t = {};
        if (quad == 0) { t[0] = (_Float16)xv; t[1] = (_Float16)1.0f; }
        bx[g] = t;
    }

    Stage sA, sB;
    load_stage<0>(sA, A1, b1, lane, quad);   // L1 stage-0 prefetch, early

    half8 binA[4][4], binB[4][4];

    // ---- layer 0: h0 = relu([x,1]·[W0;b0]) -> binA
    // mtp-staged: peak acc = 32 regs (NOT one 128-reg cluster -- that spike
    // capped residency at 2 waves/SIMD in R12).
    const f32x4 zero4 = {0.f, 0.f, 0.f, 0.f};
#pragma unroll
    for (int mtp = 0; mtp < 4; ++mtp) {
        f32x4 acc[4][2];
        __builtin_amdgcn_s_setprio(1);
#pragma unroll
        for (int hh = 0; hh < 2; ++hh)
#pragma unroll
            for (int g = 0; g < 4; ++g)
                acc[g][hh] = __builtin_amdgcn_mfma_f32_16x16x32_f16(aL0[2 * mtp + hh], bx[g], zero4, 0, 0, 0);
        __builtin_amdgcn_s_setprio(0);
#pragma unroll
        for (int g = 0; g < 4; ++g)
#pragma unroll
            for (int p = 0; p < 4; ++p) {
                half2v hv = relu_cvt2(acc[g][p >> 1][2 * (p & 1)], acc[g][p >> 1][2 * (p & 1) + 1]);
                binA[g][mtp][2 * p]     = hv[0];
                binA[g][mtp][2 * p + 1] = hv[1];
            }
    }

    // ---- layer 1 (binA -> binB), loads always one stage ahead
    load_stage<1>(sB, A1, b1, lane, quad);
    mfma_stage<0>(binA, binB, sA);
    load_stage<2>(sA, A1, b1, lane, quad);
    mfma_stage<1>(binA, binB, sB);
    load_stage<3>(sB, A1, b1, lane, quad);
    mfma_stage<2>(binA, binB, sA);
    load_stage<0>(sA, A2, b2, lane, quad);   // cross-layer prefetch
    mfma_stage<3>(binA, binB, sB);

    // ---- layer 2 (binB -> binA)
    load_stage<1>(sB, A2, b2, lane, quad);
    mfma_stage<0>(binB, binA, sA);
    load_stage<2>(sA, A2, b2, lane, quad);
    mfma_stage<1>(binB, binA, sB);
    load_stage<3>(sB, A2, b2, lane, quad);
    mfma_stage<2>(binB, binA, sA);
    load_stage<0>(sA, A3, b3, lane, quad);
    mfma_stage<3>(binB, binA, sB);

    // ---- layer 3 (binA -> binB)
    load_stage<1>(sB, A3, b3, lane, quad);
    mfma_stage<0>(binA, binB, sA);
    load_stage<2>(sA, A3, b3, lane, quad);
    mfma_stage<1>(binA, binB, sB);
    load_stage<3>(sB, A3, b3, lane, quad);
    mfma_stage<2>(binA, binB, sA);
    // L4 prefetch during L3's last stage
    half8 a4[4];
#pragma unroll
    for (int ks = 0; ks < 4; ++ks)
        a4[ks] = *(const half8*)(Af + 49152 + ks * 512 + lane * 8);
    f32x4 b4init;
#pragma unroll
    for (int r = 0; r < 4; ++r) {
        int comp = quad * 4 + r;
        b4init[r] = (comp < 14) ? b4v[comp] : 0.0f;
    }
    mfma_stage<3>(binA, binB, sB);

    // ---- layer 4: phi = W4^T·h + b4 (binB -> phis)
    {
        f32x4 acc4[4];
        __builtin_amdgcn_s_setprio(1);
#pragma unroll
        for (int g = 0; g < 4; ++g)
            acc4[g] = __builtin_amdgcn_mfma_f32_16x16x32_f16(a4[0], binB[g][0], b4init, 0, 0, 0);
#pragma unroll
        for (int ks = 1; ks < 4; ++ks)
#pragma unroll
            for (int g = 0; g < 4; ++g)
                acc4[g] = __builtin_amdgcn_mfma_f32_16x16x32_f16(a4[ks], binB[g][ks], acc4[g], 0, 0, 0);
        __builtin_amdgcn_s_setprio(0);
#pragma unroll
        for (int g = 0; g < 4; ++g)
            *(f32x4*)&phis[wid * 64 + g * 16 + col][quad * 4] = acc4[g];
    }

    // NO __syncthreads: wave wid wrote phis rows [wid*64, wid*64+64) and the
    // spline threads for those rows are the same wave -> intra-wave LDS
    // program order (lgkmcnt) is sufficient. Waves stay fully decoupled.

    // ---- RQS inverse: all 256 threads, one sample each
    if (gs < N) {
        float ph[16];
        *(f32x4*)&ph[0]  = *(const f32x4*)&phis[tid][0];
        *(f32x4*)&ph[4]  = *(const f32x4*)&phis[tid][4];
        *(f32x4*)&ph[8]  = *(const f32x4*)&phis[tid][8];
        *(f32x4*)&ph[12] = *(const f32x4*)&phis[tid][12];

        float mw = ph[0], mh = ph[5];
#pragma unroll
        for (int i = 1; i < 5; ++i) { mw = fmaxf(mw, ph[i]); mh = fmaxf(mh, ph[5 + i]); }
        float ew[5], eh[5];
        float sw = 0.f, sh = 0.f;
#pragma unroll
        for (int i = 0; i < 5; ++i) {
            ew[i] = __expf(ph[i] - mw);      sw += ew[i];
            eh[i] = __expf(ph[5 + i] - mh);  sh += eh[i];
        }
        float iw = 10.0f / sw, ih = 10.0f / sh;
        float xk[6], yk[6], dk[6];
        xk[0] = -5.0f; yk[0] = -5.0f;
#pragma unroll
        for (int i = 0; i < 5; ++i) {
            xk[i + 1] = xk[i] + ew[i] * iw;
            yk[i + 1] = yk[i] + eh[i] * ih;
        }
        dk[0] = 1.0f; dk[5] = 1.0f;
#pragma unroll
        for (int i = 0; i < 4; ++i) {
            float v = ph[10 + i];
            dk[i + 1] = 0.0001f + fmaxf(v, 0.0f) + __logf(1.0f + __expf(-fabsf(v)));
        }
        float zc = fminf(fmaxf(zv, -5.0f), 5.0f);
        int k = 0;
#pragma unroll
        for (int i = 1; i <= 4; ++i) k += (zc >= yk[i]) ? 1 : 0;
        float x0 = xk[0], x1 = xk[1], y0 = yk[0], y1 = yk[1], d0 = dk[0], d1 = dk[1];
#pragma unroll
        for (int i = 1; i < 5; ++i)
            if (k == i) { x0 = xk[i]; x1 = xk[i + 1]; y0 = yk[i]; y1 = yk[i + 1]; d0 = dk[i]; d1 = dk[i + 1]; }
        float dx = x1 - x0, dy = y1 - y0;
        float s  = dy / dx;
        float tt = zc - y0;
        float mm = d0 + d1 - 2.0f * s;
        float aa = dy * (s - d0) + tt * mm;
        float bb2 = dy * d0 - tt * mm;
        float cc = -s * tt;
        float disc = fmaxf(bb2 * bb2 - 4.0f * aa * cc, 0.0f);
        float xi   = (2.0f * cc) / (-bb2 - sqrtf(disc));
        float xin  = x0 + xi * dx;
        y[gs] = (fabsf(zv) >= 5.0f) ? zv : xin;
    }
}

extern "C" void kernel_launch(void* const* d_in, const int* in_sizes, int n_in,
                              void* d_out, int out_size, void* d_ws, size_t ws_size,
                              hipStream_t stream) {
    const float* x  = (const float*)d_in[0];
    const float* z  = (const float*)d_in[1];
    const float* W0 = (const float*)d_in[2];
    const float* b0 = (const float*)d_in[3];
    const float* W1 = (const float*)d_in[4];
    const float* b1 = (const float*)d_in[5];
    const float* W2 = (const float*)d_in[6];
    const float* b2 = (const float*)d_in[7];
    const float* W3 = (const float*)d_in[8];
    const float* b3 = (const float*)d_in[9];
    const float* W4 = (const float*)d_in[10];
    const float* b4 = (const float*)d_in[11];
    float* y = (float*)d_out;
    int N = in_sizes[0];

    _Float16* wsH = (_Float16*)d_ws;
    prep_kernel<<<27, 256, 0, stream>>>(W1, W2, W3, W4, W0, b0, wsH);
    int nblk = (N + 255) / 256;
    nflow_kernel<<<nblk, 256, 0, stream>>>(x, z, b1, b2, b3, b4, wsH, y, N);
}